// Round 6
// baseline (167.972 us; speedup 1.0000x reference)
//
#include <hip/hip_runtime.h>
#include <math.h>

#define BATCH 4
#define NCH 4
#define H 160
#define W 160
#define NPIX (H * W)          // 25600
#define NTILE (NPIX / 256)    // 100 tiles of 256 pixels
#define NWORD (NPIX / 64)     // 400 ballot words per image
#define PRE_K 2048
#define TOPK 500
#define PROB_T 0.75f
#define IOU_T 0.5f
#define COV 10.0f

#define KA_BLOCKS 16          // position coverage = 4096 >= max(F, PRE_K)
#define LCAP 1024             // per-wave key-list cap; F/4 ~ 375 expected, >10 sigma margin

// ---- workspace layout (bytes) ----
#define F_OFF     0u             // int  [B]
#define CSC_OFF   64u            // f32  [B][PRE_K]
#define CBOX_OFF  32832u         // f32  [B][PRE_K][4]
#define SUP_OFF   163904u        // u32  [B][PRE_K][64]
#define FLAG_OFF  2261056u       // u8   [B][PRE_K]

// out layout (floats)
#define OUT_HEAT_OFF 0
#define OUT_MASK_OFF 102400
#define OUT_BOX_OFF  512000
#define OUT_VAL_OFF  520000

#define TILE 16
#define TPL (W / TILE)

typedef unsigned long long u64;
typedef unsigned int u32;

__device__ __forceinline__ int block_scan_excl(int v, int tid, int* tmp, int* total) {
    tmp[tid] = v;
    __syncthreads();
    for (int off = 1; off < 256; off <<= 1) {
        int y = (tid >= off) ? tmp[tid - off] : 0;
        __syncthreads();
        tmp[tid] += y;
        __syncthreads();
    }
    int incl = tmp[tid];
    *total = tmp[255];
    __syncthreads();
    return incl - v;
}

// kA: fused score + wave-private compaction + exact rank + candidate emission +
// mask copy. 16 blocks/image, each redundantly scores the full image (0.4 MB,
// L2-broadcast) with ZERO barriers in the loop: each wave appends its frontal
// keys to its own LDS region (ballot + running register count) and writes its
// own ballot words. Every block builds the IDENTICAL (wave,tile,lane)-ordered
// list structure -> position-based partitioning is consistent (no R3 bug, no
// R4 barrier chain). Rank = count of strictly-greater keys over the 4 lists.
__global__ void __launch_bounds__(256)
kA(const float* __restrict__ mask, const float* __restrict__ bias,
   float* __restrict__ out_mask, int* __restrict__ Fout,
   float* __restrict__ cand_score, float* __restrict__ cand_box) {
    int b = blockIdx.y, bx = blockIdx.x, tid = threadIdx.x;
    int lane = tid & 63, wv = tid >> 6;
    __shared__ u64 klist[4 * LCAP];   // 32 KB, per-wave regions
    __shared__ u64 bm_s[NWORD];       // 3.2 KB
    __shared__ int wtot[4];
    __shared__ int bc[NTILE];
    __shared__ int tpre[NTILE + 1];

    const float* mp = mask + (size_t)b * NCH * NPIX;
    float* op = out_mask + (size_t)b * NCH * NPIX;
    int wbase = 0;                    // wave-uniform running frontal count
    for (int it = 0; it < NTILE; ++it) {
        int pix = it * 256 + tid;
        float x0 = mp[pix], x1 = mp[NPIX + pix];
        float x2 = mp[2 * NPIX + pix], x3 = mp[3 * NPIX + pix];
        if (it % KA_BLOCKS == bx) {   // mask passthrough, sliced across blocks
            op[pix] = x0; op[NPIX + pix] = x1;
            op[2 * NPIX + pix] = x2; op[3 * NPIX + pix] = x3;
        }
        float mx = x0; int c = 0;
        if (x1 > mx) { mx = x1; c = 1; }
        if (x2 > mx) { mx = x2; c = 2; }
        if (x3 > mx) { mx = x3; c = 3; }
        float sum = ((expf(x0 - mx) + expf(x1 - mx)) + expf(x2 - mx)) + expf(x3 - mx);
        float prob = 1.0f / sum;
        bool fr = (c != 0) && (prob > PROB_T);
        u64 bm = __ballot(fr);
        if (lane == 0) bm_s[it * 4 + wv] = bm;          // wave-private word
        if (fr) {
            int pos = wbase + __popcll(bm & ((1ull << lane) - 1ull));
            if (pos < LCAP)
                klist[wv * LCAP + pos] = ((u64)__float_as_uint(prob) << 32)
                                       | (u64)(0x7FFFFFFFu - (u32)pix);
        }
        wbase += __popcll(bm);        // wave-uniform
    }
    if (lane == 0) wtot[wv] = wbase;
    __syncthreads();

    // per-tile frontal counts + exclusive prefix (parallel, one-shot)
    for (int t = tid; t < NTILE; t += 256)
        bc[t] = __popcll(bm_s[t * 4]) + __popcll(bm_s[t * 4 + 1])
              + __popcll(bm_s[t * 4 + 2]) + __popcll(bm_s[t * 4 + 3]);
    __syncthreads();
    if (tid <= NTILE) {
        int acc = 0;
        for (int k = 0; k < tid; ++k) acc += bc[k];
        tpre[tid] = acc;
    }
    __syncthreads();

    int c0 = wtot[0], c1 = wtot[1], c2 = wtot[2], c3 = wtot[3];
    int F = c0 + c1 + c2 + c3;
    if (tid == 0 && bx == 0) Fout[b] = F;

    const float* bb = bias + (size_t)b * 4 * NPIX;
    int i = bx * 256 + tid;           // candidate list position / output slot

    if (i < F) {
        // locate (wave, index) of candidate i in the concatenated lists
        int w, k;
        if (i < c0)                { w = 0; k = i; }
        else if (i < c0 + c1)      { w = 1; k = i - c0; }
        else if (i < c0 + c1 + c2) { w = 2; k = i - c0 - c1; }
        else                       { w = 3; k = i - c0 - c1 - c2; }
        if (k < LCAP) {               // (overflow beyond LCAP: ~impossible)
            u64 ki = klist[w * LCAP + k];
            int rank = 0;
            #pragma unroll
            for (int w2 = 0; w2 < 4; ++w2) {
                int n2 = wtot[w2]; if (n2 > LCAP) n2 = LCAP;
                int base2 = w2 * LCAP;
                int kk = 0;
                for (; kk + 8 <= n2; kk += 8) {
                    rank += (klist[base2 + kk]     > ki) ? 1 : 0;
                    rank += (klist[base2 + kk + 1] > ki) ? 1 : 0;
                    rank += (klist[base2 + kk + 2] > ki) ? 1 : 0;
                    rank += (klist[base2 + kk + 3] > ki) ? 1 : 0;
                    rank += (klist[base2 + kk + 4] > ki) ? 1 : 0;
                    rank += (klist[base2 + kk + 5] > ki) ? 1 : 0;
                    rank += (klist[base2 + kk + 6] > ki) ? 1 : 0;
                    rank += (klist[base2 + kk + 7] > ki) ? 1 : 0;
                }
                for (; kk < n2; ++kk) rank += (klist[base2 + kk] > ki) ? 1 : 0;
            }
            if (rank < PRE_K) {
                float si = __uint_as_float((u32)(ki >> 32));
                int xi = 0x7FFFFFFF - (int)(u32)(ki & 0xFFFFFFFFu);
                cand_score[(size_t)b * PRE_K + rank] = si;
                float y = (float)(xi / W), x = (float)(xi % W);
                float4 box;
                box.x = y + bb[0 * NPIX + xi];
                box.y = x + bb[1 * NPIX + xi];
                box.z = y + bb[2 * NPIX + xi];
                box.w = x + bb[3 * NPIX + xi];
                ((float4*)cand_box)[(size_t)b * PRE_K + rank] = box;
            }
        }
    } else if (i >= F && i < PRE_K) {
        // padding slot: (i-F)-th non-frontal pixel in raster order (from bitmask)
        int j = i - F;
        int t = 0;
        for (; t < NTILE - 1; ++t) {
            int nf_next = (t + 1) * 256 - tpre[t + 1];  // non-frontal in tiles 0..t
            if (j < nf_next) break;
        }
        int jj = j - (t * 256 - tpre[t]);               // index within tile t
        int pix = 0;
        for (int w2 = t * 4; w2 < t * 4 + 4; ++w2) {
            u64 bm = bm_s[w2];
            int nz = 64 - __popcll(bm);
            if (jj < nz) {
                u64 x = bm;
                for (int q = 0; q < jj; ++q) x |= x + 1;  // set jj lowest zeros
                pix = w2 * 64 + __builtin_ctzll(~x);
                break;
            }
            jj -= nz;
        }
        cand_score[(size_t)b * PRE_K + i] = -1.0f;
        float y = (float)(pix / W), x = (float)(pix % W);
        float4 box;
        box.x = y + bb[0 * NPIX + pix];
        box.y = x + bb[1 * NPIX + pix];
        box.z = y + bb[2 * NPIX + pix];
        box.w = x + bb[3 * NPIX + pix];
        ((float4*)cand_box)[(size_t)b * PRE_K + i] = box;
    }
}

// kB: suppression bitmatrix, row-contiguous; per-row nonzero flag; gated stores.
__global__ void __launch_bounds__(512)
kB(const float* __restrict__ cand_box, const int* __restrict__ Fout,
   u32* __restrict__ sup, unsigned char* __restrict__ flag) {
    int b = blockIdx.y;
    int F = Fout[b];
    int V = F < PRE_K ? F : PRE_K;
    int r0 = blockIdx.x * 8;
    if (r0 >= V) return;
    __shared__ float ly1[PRE_K], lx1[PRE_K], ly2[PRE_K], lx2[PRE_K], lar[PRE_K];
    for (int k = threadIdx.x; k < PRE_K; k += 512) {
        float4 v = ((const float4*)cand_box)[(size_t)b * PRE_K + k];
        ly1[k] = v.x; lx1[k] = v.y; ly2[k] = v.z; lx2[k] = v.w;
        lar[k] = (v.z - v.x) * (v.w - v.y);
    }
    __syncthreads();
    int lr = threadIdx.x >> 6;
    int w = threadIdx.x & 63;
    int i = r0 + lr;
    float ay1 = ly1[i], ax1 = lx1[i], ay2 = ly2[i], ax2 = lx2[i], aa = lar[i];
    u32 bits = 0;
    int jbase = w * 32;
    #pragma unroll 4
    for (int jj = 0; jj < 32; ++jj) {
        int jo = (jj + w) & 31;              // bank-conflict-free rotation
        int j = jbase + jo;
        if (j > i) {
            float lty = fmaxf(ay1, ly1[j]);
            float ltx = fmaxf(ax1, lx1[j]);
            float rby = fminf(ay2, ly2[j]);
            float rbx = fminf(ax2, lx2[j]);
            float wy = fmaxf(rby - lty, 0.0f);
            float wx = fmaxf(rbx - ltx, 0.0f);
            float inter = wy * wx;
            float iou = inter / ((aa + lar[j]) - inter);
            if (iou > IOU_T) bits |= (1u << jo);
        }
    }
    bool any = __any(bits != 0u);
    if (any) sup[((size_t)b * PRE_K + i) * 64 + w] = bits;
    if (w == 0) flag[(size_t)b * PRE_K + i] = any ? 1 : 0;
}

// kC: merged NMS + finalize + heat. Every block (100 per image) redundantly runs
// the serial NMS chain (L2-broadcast reads of flagged sup rows), builds kept
// params in LDS, then renders its 16x16 heat tile. Block x==0 writes boxes/valid.
__global__ void __launch_bounds__(256)
kC(const u32* __restrict__ sup, const unsigned char* __restrict__ flag,
   const int* __restrict__ Fout, const float* __restrict__ cand_score,
   const float* __restrict__ cand_box, float* __restrict__ out_boxes,
   float* __restrict__ out_valid, float* __restrict__ heat) {
    int b = blockIdx.y, bx = blockIdx.x, tid = threadIdx.x;
    int F = Fout[b];
    int V = F < PRE_K ? F : PRE_K;

    __shared__ int rid_s[PRE_K];
    __shared__ int M_s;
    __shared__ u32 kws[64];
    __shared__ int tmp[256];
    __shared__ float plocal[TOPK * 5];
    __shared__ float lp[TOPK * 5];
    __shared__ int cnum;

    // ---- phase 1: flagged-row compaction + serial NMS chain (wave 0) ----
    if (tid < 64) {
        int lane = tid;
        const u32* f32p = (const u32*)(flag + (size_t)b * PRE_K);
        u32 fw[8];
        #pragma unroll
        for (int k = 0; k < 8; ++k) fw[k] = f32p[lane * 8 + k];
        int r0 = lane * 32;
        int cnt = 0;
        #pragma unroll
        for (int k = 0; k < 8; ++k)
            #pragma unroll
            for (int j = 0; j < 4; ++j) {
                int r = r0 + k * 4 + j;
                if (((fw[k] >> (8 * j)) & 0xFFu) != 0u && r < V) ++cnt;
            }
        int incl = cnt;
        for (int off = 1; off < 64; off <<= 1) {
            int y = __shfl_up(incl, off);
            if (lane >= off) incl += y;
        }
        if (lane == 63) M_s = incl;
        int pos = incl - cnt;
        #pragma unroll
        for (int k = 0; k < 8; ++k)
            #pragma unroll
            for (int j = 0; j < 4; ++j) {
                int r = r0 + k * 4 + j;
                if (((fw[k] >> (8 * j)) & 0xFFu) != 0u && r < V) rid_s[pos++] = r;
            }

        int M = M_s;   // wave-synchronous: lane 63 of this same wave wrote it
        int rem = V - lane * 32;
        u32 kw = (rem >= 32) ? 0xFFFFFFFFu : (rem <= 0 ? 0u : ((1u << rem) - 1u));
        const u32* supb = sup + (size_t)b * PRE_K * 64 + lane;
        int C = (M + 7) >> 3;
        int C4 = (C + 3) & ~3;
        int l7 = lane & 7;
        u32 rbuf[4][8];
        int ridv[4];

        #define LOAD_RID(slot, c) ridv[slot] = rid_s[min((c) * 8 + l7, PRE_K - 1)]
        #define ISSUE(slot) do { \
            _Pragma("unroll") \
            for (int k_ = 0; k_ < 8; ++k_) { \
                int i_ = __builtin_amdgcn_readlane(ridv[slot], k_) & (PRE_K - 1); \
                rbuf[slot][k_] = supb[(size_t)i_ * 64]; \
            } \
        } while (0)
        #define PROC(slot, c) do { \
            _Pragma("unroll") \
            for (int k_ = 0; k_ < 8; ++k_) { \
                int m_ = (c) * 8 + k_; \
                if (m_ < M) { \
                    int i_ = __builtin_amdgcn_readlane(ridv[slot], k_) & (PRE_K - 1); \
                    u32 kb_ = (u32)__builtin_amdgcn_readlane((int)kw, i_ >> 5); \
                    if ((kb_ >> (i_ & 31)) & 1u) kw &= ~rbuf[slot][k_]; \
                } \
            } \
        } while (0)

        LOAD_RID(0, 0); LOAD_RID(1, 1); LOAD_RID(2, 2); LOAD_RID(3, 3);
        ISSUE(0); ISSUE(1); ISSUE(2);
        for (int c = 0; c < C4; c += 4) {
            PROC(0, c);     ISSUE(3);            LOAD_RID(0, c + 4);
            PROC(1, c + 1); ISSUE(0);            LOAD_RID(1, c + 5);
            PROC(2, c + 2); ISSUE(1);            LOAD_RID(2, c + 6);
            PROC(3, c + 3); ISSUE(2);            LOAD_RID(3, c + 7);
        }
        #undef LOAD_RID
        #undef ISSUE
        #undef PROC
        kws[lane] = kw;
    }
    if (tid == 0) cnum = 0;
    __syncthreads();

    // ---- phase 2: finalize (params in LDS; global writes by block x==0) ----
    bool writer = (bx == 0);
    int s0 = tid * 8;
    int bits8 = (int)((kws[s0 >> 5] >> (s0 & 31)) & 0xFFu);
    int cnt = __popc(bits8);
    int tot;
    int kpre = block_scan_excl(cnt, tid, tmp, &tot);
    int NK = tot;
    for (int k = 0; k < 8; ++k) {
        int s = s0 + k;
        int kept = (bits8 >> k) & 1;
        int pos = kept ? kpre : (NK + s - kpre);
        if (pos < TOPK) {
            if (kept) {
                float4 bb4 = ((const float4*)cand_box)[(size_t)b * PRE_K + s];
                float scv = cand_score[(size_t)b * PRE_K + s];
                float* q = plocal + pos * 5;
                q[0] = (bb4.x + bb4.z) * 0.5f;
                q[1] = (bb4.y + bb4.w) * 0.5f;
                q[2] = COV / (bb4.z - bb4.x);
                q[3] = COV / (bb4.w - bb4.y);
                q[4] = scv;
                if (writer) {
                    ((float4*)out_boxes)[(size_t)b * TOPK + pos] = bb4;
                    out_valid[(size_t)b * TOPK + pos] = 1.0f;
                }
            } else if (writer) {
                float4 bb4 = ((const float4*)cand_box)[(size_t)b * PRE_K + s];
                ((float4*)out_boxes)[(size_t)b * TOPK + pos] = bb4;
                out_valid[(size_t)b * TOPK + pos] = 0.0f;
            }
        }
        kpre += kept;
    }
    __syncthreads();

    // ---- phase 3: heat tile with per-tile Gaussian culling ----
    int nv = NK < TOPK ? NK : TOPK;
    int ty0 = (bx / TPL) * TILE;
    int tx0 = (bx % TPL) * TILE;
    for (int t = tid; t < nv; t += 256) {
        const float* pp = plocal + t * 5;
        float muy = pp[0], mux = pp[1], ivy = pp[2], ivx = pp[3], p = pp[4];
        float cy = fmaxf(fmaxf((float)ty0 - muy, muy - (float)(ty0 + TILE - 1)), 0.0f);
        float cx = fmaxf(fmaxf((float)tx0 - mux, mux - (float)(tx0 + TILE - 1)), 0.0f);
        float zy = cy * fabsf(ivy);
        float zx = cx * fabsf(ivx);
        float z2 = zy * zy + zx * zx;
        if (!(z2 > 40.0f)) {                 // keep NaN cases
            int idx = atomicAdd(&cnum, 1);
            float* q = lp + idx * 5;
            q[0] = muy; q[1] = mux; q[2] = ivy; q[3] = ivx; q[4] = p;
        }
    }
    __syncthreads();
    int n = cnum;
    float py = (float)(ty0 + (tid >> 4));
    float px = (float)(tx0 + (tid & 15));
    float m = 0.0f;
    for (int t = 0; t < n; ++t) {
        float muy = lp[t * 5 + 0], mux = lp[t * 5 + 1];
        float ivy = lp[t * 5 + 2], ivx = lp[t * 5 + 3];
        float p = lp[t * 5 + 4];
        float zy = (py - muy) * ivy;
        float zx = (px - mux) * ivx;
        float g = expf(-0.5f * (zy * zy + zx * zx)) * p;
        m = fmaxf(m, g);
    }
    heat[(size_t)b * NPIX + (ty0 + (tid >> 4)) * W + tx0 + (tid & 15)] = m;
}

extern "C" void kernel_launch(void* const* d_in, const int* in_sizes, int n_in,
                              void* d_out, int out_size, void* d_ws, size_t ws_size,
                              hipStream_t stream) {
    const float* mask = (const float*)d_in[0];
    const float* bias = (const float*)d_in[1];
    float* out = (float*)d_out;
    char* ws = (char*)d_ws;

    int*   Fout       = (int*)(ws + F_OFF);
    float* cand_score = (float*)(ws + CSC_OFF);
    float* cand_box   = (float*)(ws + CBOX_OFF);
    u32*   sup        = (u32*)(ws + SUP_OFF);
    unsigned char* flag = (unsigned char*)(ws + FLAG_OFF);

    kA<<<dim3(KA_BLOCKS, BATCH), 256, 0, stream>>>(mask, bias, out + OUT_MASK_OFF,
                                                   Fout, cand_score, cand_box);
    kB<<<dim3(PRE_K / 8, BATCH), 512, 0, stream>>>(cand_box, Fout, sup, flag);
    kC<<<dim3(NTILE, BATCH), 256, 0, stream>>>(sup, flag, Fout, cand_score, cand_box,
                                               out + OUT_BOX_OFF, out + OUT_VAL_OFF,
                                               out + OUT_HEAT_OFF);
}

// Round 7
// 111.748 us; speedup vs baseline: 1.5031x; 1.5031x over previous
//
#include <hip/hip_runtime.h>
#include <math.h>

#define BATCH 4
#define NCH 4
#define H 160
#define W 160
#define NPIX (H * W)          // 25600
#define NTILE (NPIX / 256)    // 100 tiles of 256 pixels
#define PRE_K 2048
#define TOPK 500
#define PROB_T 0.75f
#define IOU_T 0.5f
#define COV 10.0f
#define RK_CH 4096

// ---- workspace layout (bytes) ----
#define FCNT_OFF  0u             // int  [B]            (zeroed via hipMemsetAsync)
#define BCNT_OFF  64u            // int  [B][NTILE]
#define BMASK_OFF 4096u          // u64  [B][NPIX/64]   frontal bitmask (12.8 KB)
#define KEY_OFF   20480u         // u64  [B][NPIX]      unordered packed (score,idx)
#define CSC_OFF   839680u        // f32  [B][PRE_K]
#define CBOX_OFF  872448u        // f32  [B][PRE_K][4]
#define SUP_OFF   1003520u       // u32  [B][PRE_K][64]
#define FLAG_OFF  3100672u       // u8   [B][PRE_K]

// out layout (floats)
#define OUT_HEAT_OFF 0
#define OUT_MASK_OFF 102400
#define OUT_BOX_OFF  512000
#define OUT_VAL_OFF  520000

#define TILE 16
#define TPL (W / TILE)

typedef unsigned long long u64;
typedef unsigned int u32;

__device__ __forceinline__ int block_scan_excl(int v, int tid, int* tmp, int* total) {
    tmp[tid] = v;
    __syncthreads();
    for (int off = 1; off < 256; off <<= 1) {
        int y = (tid >= off) ? tmp[tid - off] : 0;
        __syncthreads();
        tmp[tid] += y;
        __syncthreads();
    }
    int incl = tmp[tid];
    *total = tmp[255];
    __syncthreads();
    return incl - v;
}

// K1: softmax-max score + mask copy + frontal bitmask + per-tile counts +
// UNORDERED key emission (one atomicAdd per block -> no ordered compaction pass).
__global__ void __launch_bounds__(256)
k_score(const float* __restrict__ mask, float* __restrict__ out_mask,
        u64* __restrict__ keys, u64* __restrict__ bmask,
        int* __restrict__ blkcnt, int* __restrict__ Fcnt) {
    int b = blockIdx.y, bx = blockIdx.x, tid = threadIdx.x;
    int pix = bx * 256 + tid;
    const float* mp = mask + (size_t)b * NCH * NPIX + pix;
    float* op = out_mask + (size_t)b * NCH * NPIX + pix;
    float x0 = mp[0], x1 = mp[NPIX], x2 = mp[2 * NPIX], x3 = mp[3 * NPIX];
    op[0] = x0; op[NPIX] = x1; op[2 * NPIX] = x2; op[3 * NPIX] = x3;
    float mx = x0; int c = 0;
    if (x1 > mx) { mx = x1; c = 1; }
    if (x2 > mx) { mx = x2; c = 2; }
    if (x3 > mx) { mx = x3; c = 3; }
    float sum = ((expf(x0 - mx) + expf(x1 - mx)) + expf(x2 - mx)) + expf(x3 - mx);
    float prob = 1.0f / sum;
    bool fr = (c != 0) && (prob > PROB_T);

    int lane = tid & 63, wv = tid >> 6;
    u64 bm = __ballot(fr);
    __shared__ int wcnt[4];
    __shared__ int wpre[4];
    __shared__ int base_s;
    if (lane == 0) {
        bmask[(size_t)b * (NPIX / 64) + bx * 4 + wv] = bm;
        wcnt[wv] = __popcll(bm);
    }
    __syncthreads();
    if (tid == 0) {
        int acc = 0;
        #pragma unroll
        for (int k = 0; k < 4; ++k) { wpre[k] = acc; acc += wcnt[k]; }
        blkcnt[b * NTILE + bx] = acc;
        base_s = (acc > 0) ? atomicAdd(&Fcnt[b], acc) : 0;
    }
    __syncthreads();
    if (fr) {
        int slot = base_s + wpre[wv] + __popcll(bm & ((1ull << lane) - 1ull));
        keys[(size_t)b * NPIX + slot] =
            ((u64)__float_as_uint(prob) << 32) | (u64)(0x7FFFFFFFu - (u32)pix);
    }
}

// K2: exact rank via u64 key compares (LDS-staged) + raster-order padding
// recovered from per-tile counts + frontal bitmask.
__global__ void __launch_bounds__(256)
k_rank(const u64* __restrict__ keys, const float* __restrict__ bias,
       const int* __restrict__ Fcnt, const int* __restrict__ blkcnt,
       const u64* __restrict__ bmask, float* __restrict__ cand_score,
       float* __restrict__ cand_box) {
    int b = blockIdx.y, bx = blockIdx.x, tid = threadIdx.x;
    int F = Fcnt[b];
    int blk0 = bx * 256;
    if (blk0 >= F && blk0 >= PRE_K) return;
    int i = blk0 + tid;
    const float* bb = bias + (size_t)b * 4 * NPIX;

    __shared__ u64 ks[RK_CH];
    if (blk0 < F) {                       // block-uniform participation in staging
        const u64* kb = keys + (size_t)b * NPIX;
        u64 ki = (i < F) ? kb[i] : 0;
        int rank = 0;
        for (int base = 0; base < F; base += RK_CH) {
            int lim = min(RK_CH, F - base);
            __syncthreads();
            for (int k = tid; k < lim; k += 256) ks[k] = kb[base + k];
            __syncthreads();
            if (i < F) {
                int k = 0;
                for (; k + 8 <= lim; k += 8) {
                    rank += (ks[k]     > ki) ? 1 : 0;
                    rank += (ks[k + 1] > ki) ? 1 : 0;
                    rank += (ks[k + 2] > ki) ? 1 : 0;
                    rank += (ks[k + 3] > ki) ? 1 : 0;
                    rank += (ks[k + 4] > ki) ? 1 : 0;
                    rank += (ks[k + 5] > ki) ? 1 : 0;
                    rank += (ks[k + 6] > ki) ? 1 : 0;
                    rank += (ks[k + 7] > ki) ? 1 : 0;
                }
                for (; k < lim; ++k) rank += (ks[k] > ki) ? 1 : 0;
            }
        }
        if (i < F && rank < PRE_K) {
            float si = __uint_as_float((u32)(ki >> 32));
            int xi = 0x7FFFFFFF - (int)(u32)(ki & 0xFFFFFFFFu);
            cand_score[(size_t)b * PRE_K + rank] = si;
            float y = (float)(xi / W), x = (float)(xi % W);
            float4 box;
            box.x = y + bb[0 * NPIX + xi];
            box.y = x + bb[1 * NPIX + xi];
            box.z = y + bb[2 * NPIX + xi];
            box.w = x + bb[3 * NPIX + xi];
            ((float4*)cand_box)[(size_t)b * PRE_K + rank] = box;
        }
    }
    // padding: slot i in [F, PRE_K) takes the (i-F)-th non-frontal pixel (raster)
    if (i >= F && i < PRE_K) {
        int j = i - F;
        const int* bc = blkcnt + b * NTILE;
        int t = 0;
        for (; t < NTILE; ++t) {
            int nf = 256 - bc[t];
            if (j < nf) break;
            j -= nf;
        }
        const u64* bmk = bmask + (size_t)b * (NPIX / 64) + t * 4;
        int pix = 0;
        #pragma unroll
        for (int w = 0; w < 4; ++w) {
            u64 bm = bmk[w];
            int nz = 64 - __popcll(bm);
            if (j < nz) {
                u64 x = bm;
                for (int q = 0; q < j; ++q) x |= x + 1;   // set j lowest zeros
                pix = t * 256 + w * 64 + __builtin_ctzll(~x);
                break;
            }
            j -= nz;
        }
        cand_score[(size_t)b * PRE_K + i] = -1.0f;
        float y = (float)(pix / W), x = (float)(pix % W);
        float4 box;
        box.x = y + bb[0 * NPIX + pix];
        box.y = x + bb[1 * NPIX + pix];
        box.z = y + bb[2 * NPIX + pix];
        box.w = x + bb[3 * NPIX + pix];
        ((float4*)cand_box)[(size_t)b * PRE_K + i] = box;
    }
}

// K3: suppression bitmatrix, row-contiguous; per-row nonzero flag; gated stores.
__global__ void __launch_bounds__(512)
k_iou(const float* __restrict__ cand_box, const int* __restrict__ Fcnt,
      u32* __restrict__ sup, unsigned char* __restrict__ flag) {
    int b = blockIdx.y;
    int F = Fcnt[b];
    int V = F < PRE_K ? F : PRE_K;
    int r0 = blockIdx.x * 8;
    if (r0 >= V) return;
    __shared__ float ly1[PRE_K], lx1[PRE_K], ly2[PRE_K], lx2[PRE_K], lar[PRE_K];
    for (int k = threadIdx.x; k < PRE_K; k += 512) {
        float4 v = ((const float4*)cand_box)[(size_t)b * PRE_K + k];
        ly1[k] = v.x; lx1[k] = v.y; ly2[k] = v.z; lx2[k] = v.w;
        lar[k] = (v.z - v.x) * (v.w - v.y);
    }
    __syncthreads();
    int lr = threadIdx.x >> 6;
    int w = threadIdx.x & 63;
    int i = r0 + lr;
    float ay1 = ly1[i], ax1 = lx1[i], ay2 = ly2[i], ax2 = lx2[i], aa = lar[i];
    u32 bits = 0;
    int jbase = w * 32;
    #pragma unroll 4
    for (int jj = 0; jj < 32; ++jj) {
        int jo = (jj + w) & 31;
        int j = jbase + jo;
        if (j > i) {
            float lty = fmaxf(ay1, ly1[j]);
            float ltx = fmaxf(ax1, lx1[j]);
            float rby = fminf(ay2, ly2[j]);
            float rbx = fminf(ax2, lx2[j]);
            float wy = fmaxf(rby - lty, 0.0f);
            float wx = fmaxf(rbx - ltx, 0.0f);
            float inter = wy * wx;
            float iou = inter / ((aa + lar[j]) - inter);
            if (iou > IOU_T) bits |= (1u << jo);
        }
    }
    bool any = __any(bits != 0u);
    if (any) sup[((size_t)b * PRE_K + i) * 64 + w] = bits;
    if (w == 0) flag[(size_t)b * PRE_K + i] = any ? 1 : 0;
}

// K4: merged NMS + finalize + heat. Every block (100 per image) REDUNDANTLY runs
// the serial NMS chain (L2-broadcast reads), builds the kept-params list in LDS,
// then renders its 16x16 heat tile. Block x==0 per image also writes boxes/valid.
__global__ void __launch_bounds__(256)
k_nmsheat(const u32* __restrict__ sup, const unsigned char* __restrict__ flag,
          const int* __restrict__ Fcnt, const float* __restrict__ cand_score,
          const float* __restrict__ cand_box, float* __restrict__ out_boxes,
          float* __restrict__ out_valid, float* __restrict__ heat) {
    int b = blockIdx.y, bx = blockIdx.x, tid = threadIdx.x;
    int F = Fcnt[b];
    int V = F < PRE_K ? F : PRE_K;

    __shared__ int rid_s[PRE_K];
    __shared__ int M_s;
    __shared__ u32 kws[64];
    __shared__ int tmp[256];
    __shared__ float plocal[TOPK * 5];
    __shared__ float lp[TOPK * 5];
    __shared__ int cnum;

    // ---- phase 1: flagged-row compaction + serial NMS chain (wave 0) ----
    if (tid < 64) {
        int lane = tid;
        const u32* f32p = (const u32*)(flag + (size_t)b * PRE_K);
        u32 fw[8];
        #pragma unroll
        for (int k = 0; k < 8; ++k) fw[k] = f32p[lane * 8 + k];
        int r0 = lane * 32;
        int cnt = 0;
        #pragma unroll
        for (int k = 0; k < 8; ++k)
            #pragma unroll
            for (int j = 0; j < 4; ++j) {
                int r = r0 + k * 4 + j;
                if (((fw[k] >> (8 * j)) & 0xFFu) != 0u && r < V) ++cnt;
            }
        int incl = cnt;
        for (int off = 1; off < 64; off <<= 1) {
            int y = __shfl_up(incl, off);
            if (lane >= off) incl += y;
        }
        if (lane == 63) M_s = incl;
        int pos = incl - cnt;
        #pragma unroll
        for (int k = 0; k < 8; ++k)
            #pragma unroll
            for (int j = 0; j < 4; ++j) {
                int r = r0 + k * 4 + j;
                if (((fw[k] >> (8 * j)) & 0xFFu) != 0u && r < V) rid_s[pos++] = r;
            }

        int M = M_s;   // wave-synchronous: M_s written by lane 63 of same wave
        int rem = V - lane * 32;
        u32 kw = (rem >= 32) ? 0xFFFFFFFFu : (rem <= 0 ? 0u : ((1u << rem) - 1u));
        const u32* supb = sup + (size_t)b * PRE_K * 64 + lane;
        int C = (M + 7) >> 3;
        int C4 = (C + 3) & ~3;
        int l7 = lane & 7;
        u32 rbuf[4][8];
        int ridv[4];

        #define LOAD_RID(slot, c) ridv[slot] = rid_s[min((c) * 8 + l7, PRE_K - 1)]
        #define ISSUE(slot) do { \
            _Pragma("unroll") \
            for (int k_ = 0; k_ < 8; ++k_) { \
                int i_ = __builtin_amdgcn_readlane(ridv[slot], k_) & (PRE_K - 1); \
                rbuf[slot][k_] = supb[(size_t)i_ * 64]; \
            } \
        } while (0)
        #define PROC(slot, c) do { \
            _Pragma("unroll") \
            for (int k_ = 0; k_ < 8; ++k_) { \
                int m_ = (c) * 8 + k_; \
                if (m_ < M) { \
                    int i_ = __builtin_amdgcn_readlane(ridv[slot], k_) & (PRE_K - 1); \
                    u32 kb_ = (u32)__builtin_amdgcn_readlane((int)kw, i_ >> 5); \
                    if ((kb_ >> (i_ & 31)) & 1u) kw &= ~rbuf[slot][k_]; \
                } \
            } \
        } while (0)

        LOAD_RID(0, 0); LOAD_RID(1, 1); LOAD_RID(2, 2); LOAD_RID(3, 3);
        ISSUE(0); ISSUE(1); ISSUE(2);
        for (int c = 0; c < C4; c += 4) {
            PROC(0, c);     ISSUE(3);            LOAD_RID(0, c + 4);
            PROC(1, c + 1); ISSUE(0);            LOAD_RID(1, c + 5);
            PROC(2, c + 2); ISSUE(1);            LOAD_RID(2, c + 6);
            PROC(3, c + 3); ISSUE(2);            LOAD_RID(3, c + 7);
        }
        #undef LOAD_RID
        #undef ISSUE
        #undef PROC
        kws[lane] = kw;
    }
    if (tid == 0) cnum = 0;
    __syncthreads();

    // ---- phase 2: finalize (params in LDS; global writes by block x==0) ----
    bool writer = (bx == 0);
    int s0 = tid * 8;
    int bits8 = (int)((kws[s0 >> 5] >> (s0 & 31)) & 0xFFu);
    int cnt = __popc(bits8);
    int tot;
    int kpre = block_scan_excl(cnt, tid, tmp, &tot);
    int NK = tot;
    for (int k = 0; k < 8; ++k) {
        int s = s0 + k;
        int kept = (bits8 >> k) & 1;
        int pos = kept ? kpre : (NK + s - kpre);
        if (pos < TOPK) {
            if (kept) {
                float4 bb4 = ((const float4*)cand_box)[(size_t)b * PRE_K + s];
                float scv = cand_score[(size_t)b * PRE_K + s];
                float* q = plocal + pos * 5;
                q[0] = (bb4.x + bb4.z) * 0.5f;
                q[1] = (bb4.y + bb4.w) * 0.5f;
                q[2] = COV / (bb4.z - bb4.x);
                q[3] = COV / (bb4.w - bb4.y);
                q[4] = scv;
                if (writer) {
                    ((float4*)out_boxes)[(size_t)b * TOPK + pos] = bb4;
                    out_valid[(size_t)b * TOPK + pos] = 1.0f;
                }
            } else if (writer) {
                float4 bb4 = ((const float4*)cand_box)[(size_t)b * PRE_K + s];
                ((float4*)out_boxes)[(size_t)b * TOPK + pos] = bb4;
                out_valid[(size_t)b * TOPK + pos] = 0.0f;
            }
        }
        kpre += kept;
    }
    __syncthreads();

    // ---- phase 3: heat tile with per-tile Gaussian culling ----
    int nv = NK < TOPK ? NK : TOPK;
    int ty0 = (bx / TPL) * TILE;
    int tx0 = (bx % TPL) * TILE;
    for (int t = tid; t < nv; t += 256) {
        const float* pp = plocal + t * 5;
        float muy = pp[0], mux = pp[1], ivy = pp[2], ivx = pp[3], p = pp[4];
        float cy = fmaxf(fmaxf((float)ty0 - muy, muy - (float)(ty0 + TILE - 1)), 0.0f);
        float cx = fmaxf(fmaxf((float)tx0 - mux, mux - (float)(tx0 + TILE - 1)), 0.0f);
        float zy = cy * fabsf(ivy);
        float zx = cx * fabsf(ivx);
        float z2 = zy * zy + zx * zx;
        if (!(z2 > 40.0f)) {                 // keep NaN cases
            int idx = atomicAdd(&cnum, 1);
            float* q = lp + idx * 5;
            q[0] = muy; q[1] = mux; q[2] = ivy; q[3] = ivx; q[4] = p;
        }
    }
    __syncthreads();
    int n = cnum;
    float py = (float)(ty0 + (tid >> 4));
    float px = (float)(tx0 + (tid & 15));
    float m = 0.0f;
    for (int t = 0; t < n; ++t) {
        float muy = lp[t * 5 + 0], mux = lp[t * 5 + 1];
        float ivy = lp[t * 5 + 2], ivx = lp[t * 5 + 3];
        float p = lp[t * 5 + 4];
        float zy = (py - muy) * ivy;
        float zx = (px - mux) * ivx;
        float g = expf(-0.5f * (zy * zy + zx * zx)) * p;
        m = fmaxf(m, g);
    }
    heat[(size_t)b * NPIX + (ty0 + (tid >> 4)) * W + tx0 + (tid & 15)] = m;
}

extern "C" void kernel_launch(void* const* d_in, const int* in_sizes, int n_in,
                              void* d_out, int out_size, void* d_ws, size_t ws_size,
                              hipStream_t stream) {
    const float* mask = (const float*)d_in[0];
    const float* bias = (const float*)d_in[1];
    float* out = (float*)d_out;
    char* ws = (char*)d_ws;

    int*   Fcnt       = (int*)(ws + FCNT_OFF);
    int*   blkcnt     = (int*)(ws + BCNT_OFF);
    u64*   bmask      = (u64*)(ws + BMASK_OFF);
    u64*   keys       = (u64*)(ws + KEY_OFF);
    float* cand_score = (float*)(ws + CSC_OFF);
    float* cand_box   = (float*)(ws + CBOX_OFF);
    u32*   sup        = (u32*)(ws + SUP_OFF);
    unsigned char* flag = (unsigned char*)(ws + FLAG_OFF);

    hipMemsetAsync(Fcnt, 0, BATCH * sizeof(int), stream);
    dim3 g100(NTILE, BATCH);
    k_score<<<g100, 256, 0, stream>>>(mask, out + OUT_MASK_OFF, keys, bmask,
                                      blkcnt, Fcnt);
    k_rank<<<g100, 256, 0, stream>>>(keys, bias, Fcnt, blkcnt, bmask,
                                     cand_score, cand_box);
    k_iou<<<dim3(PRE_K / 8, BATCH), 512, 0, stream>>>(cand_box, Fcnt, sup, flag);
    k_nmsheat<<<g100, 256, 0, stream>>>(sup, flag, Fcnt, cand_score, cand_box,
                                        out + OUT_BOX_OFF, out + OUT_VAL_OFF,
                                        out + OUT_HEAT_OFF);
}